// Round 3
// baseline (6012.434 us; speedup 1.0000x reference)
//
#include <hip/hip_runtime.h>
#include <hip/hip_cooperative_groups.h>

namespace cg = cooperative_groups;

// TGV prox primal-dual, 30 iterations on (3,512,512) fp32.
//
// Primary path: PERSISTENT COOPERATIVE kernel — one launch, 30 iterations with
// grid.sync() + explicit agent-scope fences between. u-state resident in LDS;
// per-iteration staging is a halo-only refresh; u interior never stored.
// Fallback path (if cooperative launch returns an error): the harness-verified
// 30-launch kernel chain (434.6us) — guarantees correctness regardless of
// cooperative-launch support.

#define H 512
#define W 512
#define C 3
#define HW (H * W)
#define CHW (C * H * W)
#define N_IT 30

#define TW 64
#define TH 16

#define TAU     0.01f
#define LAM2    0.15f
#define RHO     1.99f
#define SIGMA   1.3888888888888888f   /* 1/TAU/72 */
#define INV_TL1 1000.0f               /* 1/(TAU*LAM1) */
#define INV_1PT (1.0f / 1.01f)        /* 1/(1+TAU) */

// u planes rows i0-2..i0+17 (20), cols j0-8..j0+67 (19 float4 chunks, lc=gj-j0+8)
#define UROWS 20
#define USTR  80
// xbar/rbar planes rows -1..16 (18), cols lc = col+4 (col -4..67)
#define BROWS 18
#define BSTR  72

// ============================ persistent cooperative ========================
__global__ __launch_bounds__(256, 3)
void tgv_all(const float* __restrict__ y,
             float* __restrict__ b0,
             float* __restrict__ b1,
             float* __restrict__ outp)
{
    cg::grid_group grid = cg::this_grid();

    __shared__ __attribute__((aligned(16))) float su[4][UROWS][USTR];
    __shared__ __attribute__((aligned(16))) float sb[3][BROWS][BSTR]; // 0=xbar 1=rbar0 2=rbar1

    const int tid = threadIdx.x;
    const int c   = blockIdx.z;
    const int i0  = blockIdx.y * TH;
    const int j0  = blockIdx.x * TW;
    const int cb  = c * HW;
    const int ty  = tid >> 4, tx = tid & 15;

    // ring task mapping (tid < 68)
    int rr2 = 0, s2 = 0;
    const bool ring = tid < 68;
    if (ring) {
        if (tid < 18)      { rr2 = -1;       s2 = 4 * tid - 4; }
        else if (tid < 36) { rr2 = TH;       s2 = 4 * (tid - 18) - 4; }
        else if (tid < 52) { rr2 = tid - 36; s2 = -4; }
        else               { rr2 = tid - 52; s2 = TW; }
    }

    // y never changes: load once (interior strip + ring strip)
    auto loady = [&](int rr, int s, float* o) {
        const int gi = i0 + rr, gjb = j0 + s;
        const bool row_ok = (unsigned)gi < H;
        if (row_ok && gjb >= 0 && gjb + 3 < W) {
            *(float4*)o = *(const float4*)(y + cb + gi * W + gjb);
        } else {
            #pragma unroll
            for (int e = 0; e < 4; ++e)
                o[e] = (row_ok && (unsigned)(gjb + e) < W) ? y[cb + gi * W + gjb + e] : 0.f;
        }
    };
    float yv[4];
    loady(ty, 4 * tx, yv);
    float yv2[4] = {0.f, 0.f, 0.f, 0.f};
    if (ring) loady(rr2, s2, yv2);

    for (int it = 1; it <= N_IT; ++it) {
        const int MODE = (it == 1) ? 0 : ((it == N_IT) ? 2 : 1);
        const float* src = (it & 1) ? b1 : b0;              // it even -> b0
        float* dst = (it == N_IT) ? outp : ((it & 1) ? b0 : b1);

        // ---- halo-only refresh of su (interior survives from last stage-2) ----
        if (MODE != 0) {
            for (int t = tid; t < 496; t += 256) {
                const int pl = t / 124;
                const int rm = t - pl * 124;
                int row, k;
                if (rm < 76) {
                    const int q = rm / 19;
                    row = (q < 2) ? q : q + 16;
                    k = rm - q * 19;
                } else {
                    const int rm2 = rm - 76;
                    const int q = rm2 / 3;
                    row = 2 + q;
                    const int kk = rm2 - q * 3;
                    k = (kk == 2) ? 18 : kk;
                }
                const int gi = i0 + row - 2;
                const int gj = j0 + 4 * k - 8;
                float4 v = make_float4(0.f, 0.f, 0.f, 0.f);
                if ((unsigned)gi < H) {
                    const float* p = src + (3 + pl) * CHW + cb + gi * W;
                    if (gj >= 0 && gj + 3 < W) {
                        v = *(const float4*)(p + gj);
                    } else {
                        float a0 = ((unsigned)(gj + 0) < W) ? p[gj + 0] : 0.f;
                        float a1 = ((unsigned)(gj + 1) < W) ? p[gj + 1] : 0.f;
                        float a2 = ((unsigned)(gj + 2) < W) ? p[gj + 2] : 0.f;
                        float a3 = ((unsigned)(gj + 3) < W) ? p[gj + 3] : 0.f;
                        v = make_float4(a0, a1, a2, a3);
                    }
                }
                *(float4*)&su[pl][row][4 * k] = v;
            }
            __syncthreads();
        }

        // ---- stage 1: x/r prox; xbar/rbar -> LDS ----
        auto strip1 = [&](int rr, int s, bool interior, const float* yv_) {
            const int gi  = i0 + rr;
            const int gjb = j0 + s;
            const bool row_ok = (unsigned)gi < H;

            float x2c[4], r0c[4], r1c[4];
            if (MODE == 0) {
                #pragma unroll
                for (int e = 0; e < 4; ++e) { x2c[e] = yv_[e]; r0c[e] = 0.f; r1c[e] = 0.f; }
            } else {
                if (row_ok && gjb >= 0 && gjb + 3 < W) {
                    const int p = cb + gi * W + gjb;
                    *(float4*)x2c = *(const float4*)(src + p);
                    *(float4*)r0c = *(const float4*)(src + CHW + p);
                    *(float4*)r1c = *(const float4*)(src + 2 * CHW + p);
                } else {
                    #pragma unroll
                    for (int e = 0; e < 4; ++e) {
                        const int gj = gjb + e;
                        const bool ok = row_ok && ((unsigned)gj < W);
                        const int p = cb + gi * W + gj;
                        x2c[e] = ok ? src[p] : 0.f;
                        r0c[e] = ok ? src[CHW + p] : 0.f;
                        r1c[e] = ok ? src[2 * CHW + p] : 0.f;
                    }
                }
            }

            float t0c[4], t1c[4], t0n[4], t1w[4];
            if (MODE == 0) {
                #pragma unroll
                for (int e = 0; e < 4; ++e) { t0c[e] = t1c[e] = t0n[e] = t1w[e] = 0.f; }
            } else {
                const int lr = rr + 2;
                const int lc = s + 8;
                float4 v;
                float u0n[4], u0c[4], u0s[4], u1n[5], u1c[5], u2r[6], u3n[5], u3c[5];
                v = *(const float4*)&su[0][lr - 1][lc]; u0n[0]=v.x; u0n[1]=v.y; u0n[2]=v.z; u0n[3]=v.w;
                v = *(const float4*)&su[0][lr    ][lc]; u0c[0]=v.x; u0c[1]=v.y; u0c[2]=v.z; u0c[3]=v.w;
                v = *(const float4*)&su[0][lr + 1][lc]; u0s[0]=v.x; u0s[1]=v.y; u0s[2]=v.z; u0s[3]=v.w;
                v = *(const float4*)&su[1][lr - 1][lc]; u1n[0]=v.x; u1n[1]=v.y; u1n[2]=v.z; u1n[3]=v.w;
                u1n[4] = su[1][lr - 1][lc + 4];
                v = *(const float4*)&su[1][lr    ][lc]; u1c[0]=v.x; u1c[1]=v.y; u1c[2]=v.z; u1c[3]=v.w;
                u1c[4] = su[1][lr][lc + 4];
                u2r[0] = su[2][lr][lc - 1];
                v = *(const float4*)&su[2][lr][lc]; u2r[1]=v.x; u2r[2]=v.y; u2r[3]=v.z; u2r[4]=v.w;
                u2r[5] = su[2][lr][lc + 4];
                u3n[0] = su[3][lr - 1][lc - 1];
                v = *(const float4*)&su[3][lr - 1][lc]; u3n[1]=v.x; u3n[2]=v.y; u3n[3]=v.z; u3n[4]=v.w;
                u3c[0] = su[3][lr][lc - 1];
                v = *(const float4*)&su[3][lr][lc]; u3c[1]=v.x; u3c[2]=v.y; u3c[3]=v.z; u3c[4]=v.w;

                const bool im0 = gi > 0, imHl = gi < H - 1;
                #pragma unroll
                for (int e = 0; e < 4; ++e) {
                    const int gj = gjb + e;
                    const bool jm0 = gj > 0;
                    t0c[e] = TAU * (u0c[e] - u0s[e] + (jm0 ? u1c[e] : 0.f) - u1c[e + 1]);
                    t1c[e] = TAU * (u2r[e + 1] - u2r[e + 2] + u3n[e + 1] - (imHl ? u3c[e + 1] : 0.f));
                    t0n[e] = im0 ? TAU * (u0n[e] - u0c[e] + (jm0 ? u1n[e] : 0.f) - u1n[e + 1]) : 0.f;
                    t1w[e] = jm0 ? TAU * (u2r[e] - u2r[e + 1] + u3n[e] - (imHl ? u3c[e] : 0.f)) : 0.f;
                }
            }

            const bool imH = gi < H - 1;
            float xnew[4], rn0[4], rn1[4], xb[4], rb0[4], rb1[4];
            #pragma unroll
            for (int e = 0; e < 4; ++e) {
                const int gj = gjb + e;
                const bool jmW = gj < W - 1;
                const float nT  = t0n[e] - (imH ? t0c[e] : 0.f) + t1w[e] - (jmW ? t1c[e] : 0.f);
                const float xv  = (x2c[e] - nT + TAU * yv_[e]) * INV_1PT;
                xb[e] = 2.f * xv - x2c[e];
                const float rp0 = r0c[e] + t0c[e];
                const float rp1 = r1c[e] + t1c[e];
                const float nrm = sqrtf(rp0 * rp0 + rp1 * rp1);
                const float f   = 1.f - 1.f / fmaxf(nrm * INV_TL1, 1.f);
                const float rv0 = rp0 * f, rv1 = rp1 * f;
                rb0[e]  = 2.f * rv0 - r0c[e];
                rb1[e]  = 2.f * rv1 - r1c[e];
                xnew[e] = x2c[e] + RHO * (xv - x2c[e]);
                rn0[e]  = r0c[e] + RHO * (rv0 - r0c[e]);
                rn1[e]  = r1c[e] + RHO * (rv1 - r1c[e]);
            }
            *(float4*)&sb[0][rr + 1][s + 4] = *(float4*)xb;
            *(float4*)&sb[1][rr + 1][s + 4] = *(float4*)rb0;
            *(float4*)&sb[2][rr + 1][s + 4] = *(float4*)rb1;

            if (interior) {
                const int p = cb + gi * W + gjb;
                if (MODE == 2) {
                    *(float4*)(dst + p) = *(float4*)xnew;
                    *(float4*)(dst + CHW + 2 * p)     = make_float4(rn0[0], rn1[0], rn0[1], rn1[1]);
                    *(float4*)(dst + CHW + 2 * p + 4) = make_float4(rn0[2], rn1[2], rn0[3], rn1[3]);
                } else {
                    *(float4*)(dst + p)           = *(float4*)xnew;
                    *(float4*)(dst + CHW + p)     = *(float4*)rn0;
                    *(float4*)(dst + 2 * CHW + p) = *(float4*)rn1;
                }
            }
        };

        strip1(ty, 4 * tx, true, yv);
        if (ring) strip1(rr2, s2, false, yv2);
        __syncthreads();

        // ---- stage 2: u prox; u-state stays resident in su ----
        {
            const int gi  = i0 + ty;
            const int gjb = j0 + 4 * tx;
            const int lr  = ty + 1;
            const int lc  = 4 * tx + 4;
            float4 v;
            float xA[6], xS[6], xN[4], r0C[5], r0N[4], r1C[5], r1S[4];
            xA[0] = sb[0][lr][lc - 1];
            v = *(const float4*)&sb[0][lr][lc]; xA[1]=v.x; xA[2]=v.y; xA[3]=v.z; xA[4]=v.w;
            xA[5] = sb[0][lr][lc + 4];
            xS[0] = sb[0][lr + 1][lc - 1];
            v = *(const float4*)&sb[0][lr + 1][lc]; xS[1]=v.x; xS[2]=v.y; xS[3]=v.z; xS[4]=v.w;
            xS[5] = sb[0][lr + 1][lc + 4];
            v = *(const float4*)&sb[0][lr - 1][lc]; xN[0]=v.x; xN[1]=v.y; xN[2]=v.z; xN[3]=v.w;
            r0C[0] = sb[1][lr][lc - 1];
            v = *(const float4*)&sb[1][lr][lc]; r0C[1]=v.x; r0C[2]=v.y; r0C[3]=v.z; r0C[4]=v.w;
            v = *(const float4*)&sb[1][lr - 1][lc]; r0N[0]=v.x; r0N[1]=v.y; r0N[2]=v.z; r0N[3]=v.w;
            r1C[0] = sb[2][lr][lc - 1];
            v = *(const float4*)&sb[2][lr][lc]; r1C[1]=v.x; r1C[2]=v.y; r1C[3]=v.z; r1C[4]=v.w;
            v = *(const float4*)&sb[2][lr + 1][lc]; r1S[0]=v.x; r1S[1]=v.y; r1S[2]=v.z; r1S[3]=v.w;

            const int lru = ty + 2, lcu = 4 * tx + 8;
            float u0o[4], u1o[4], u2o[4], u3o[4];
            if (MODE == 0) {
                #pragma unroll
                for (int e = 0; e < 4; ++e) { u0o[e] = u1o[e] = u2o[e] = u3o[e] = 0.f; }
            } else {
                v = *(const float4*)&su[0][lru][lcu]; u0o[0]=v.x; u0o[1]=v.y; u0o[2]=v.z; u0o[3]=v.w;
                v = *(const float4*)&su[1][lru][lcu]; u1o[0]=v.x; u1o[1]=v.y; u1o[2]=v.z; u1o[3]=v.w;
                v = *(const float4*)&su[2][lru][lcu]; u2o[0]=v.x; u2o[1]=v.y; u2o[2]=v.z; u2o[3]=v.w;
                v = *(const float4*)&su[3][lru][lcu]; u3o[0]=v.x; u3o[1]=v.y; u3o[2]=v.z; u3o[3]=v.w;
            }

            const bool im0 = gi > 0, imH = gi < H - 1;
            float un0[4], un1[4], un2[4], un3[4];
            #pragma unroll
            for (int e = 0; e < 4; ++e) {
                const int gj = gjb + e;
                const bool jm0 = gj > 0, jmW = gj < W - 1;
                const float xC = xA[e + 1], xE = xA[e + 2], xW_ = xA[e];
                const float I0c = (imH ? xS[e + 1] - xC : 0.f) - r0C[e + 1];
                const float I0n = im0 ? (xC - xN[e] - r0N[e]) : 0.f;
                const float I0w = jm0 ? ((imH ? xS[e] - xW_ : 0.f) - r0C[e]) : 0.f;
                const float I1c = (jmW ? xE - xC : 0.f) - r1C[e + 1];
                const float I1w = jm0 ? (xC - xW_ - r1C[e]) : 0.f;
                const float I1s = imH ? ((jmW ? xS[e + 2] - xS[e + 1] : 0.f) - r1S[e]) : 0.f;
                const float g0 = I0c - I0n;
                const float g1 = jm0 ? (I0c - I0w) : 0.f;
                const float g2 = I1c - I1w;
                const float g3 = imH ? (I1s - I1c) : 0.f;
                const float up0 = u0o[e] + SIGMA * g0;
                const float up1 = u1o[e] + SIGMA * g1;
                const float up2 = u2o[e] + SIGMA * g2;
                const float up3 = u3o[e] + SIGMA * g3;
                const float nrm = sqrtf(up0 * up0 + up1 * up1 + up2 * up2 + up3 * up3);
                const float inv = 1.f / fmaxf(nrm * (1.0f / LAM2), 1.f);
                un0[e] = u0o[e] + RHO * (up0 * inv - u0o[e]);
                un1[e] = u1o[e] + RHO * (up1 * inv - u1o[e]);
                un2[e] = u2o[e] + RHO * (up2 * inv - u2o[e]);
                un3[e] = u3o[e] + RHO * (up3 * inv - u3o[e]);
            }

            // keep u-state resident
            *(float4*)&su[0][lru][lcu] = *(float4*)un0;
            *(float4*)&su[1][lru][lcu] = *(float4*)un1;
            *(float4*)&su[2][lru][lcu] = *(float4*)un2;
            *(float4*)&su[3][lru][lcu] = *(float4*)un3;

            const int p = cb + gi * W + gjb;
            if (MODE == 2) {
                #pragma unroll
                for (int e = 0; e < 4; ++e)
                    *(float4*)(dst + 3 * CHW + 4 * (p + e)) =
                        make_float4(un0[e], un1[e], un2[e], un3[e]);
            } else if (ty < 2 || ty >= 14 || tx == 0 || tx >= 14) {
                // only border cells are read by neighbors' halo refresh
                *(float4*)(dst + 3 * CHW + p) = *(float4*)un0;
                *(float4*)(dst + 4 * CHW + p) = *(float4*)un1;
                *(float4*)(dst + 5 * CHW + p) = *(float4*)un2;
                *(float4*)(dst + 6 * CHW + p) = *(float4*)un3;
            }
        }

        if (it != N_IT) {
            __threadfence();   // release: drain stores past XCD L2 (device scope)
            grid.sync();
            __threadfence();   // acquire: invalidate L1/L2 before halo reads
        }
    }
}

// ======================= verified multi-launch fallback =====================
template <int MODE> // 0 = first iter, 1 = middle, 2 = last (dst = d_out interleaved)
__global__ __launch_bounds__(256)
void fused_it(const float* __restrict__ y,
              const float* __restrict__ src,
              float* __restrict__ dst)
{
    __shared__ float su[4][UROWS][USTR];
    __shared__ float sb[3][BROWS][BSTR];

    const int tid = threadIdx.x;
    const int c   = blockIdx.z;
    const int i0  = blockIdx.y * TH;
    const int j0  = blockIdx.x * TW;
    const int cb  = c * HW;

    if (MODE != 0) {
        for (int t = tid; t < 4 * UROWS * 19; t += 256) {
            const int pl  = t / (UROWS * 19);
            const int rm  = t - pl * (UROWS * 19);
            const int row = rm / 19;
            const int k   = rm - row * 19;
            const int gi  = i0 + row - 2;
            const int gj  = j0 + 4 * k - 8;
            float4 v = make_float4(0.f, 0.f, 0.f, 0.f);
            if ((unsigned)gi < H) {
                const float* p = src + (3 + pl) * CHW + cb + gi * W;
                if (gj >= 0 && gj + 3 < W) {
                    v = *(const float4*)(p + gj);
                } else {
                    float a0 = ((unsigned)(gj + 0) < W) ? p[gj + 0] : 0.f;
                    float a1 = ((unsigned)(gj + 1) < W) ? p[gj + 1] : 0.f;
                    float a2 = ((unsigned)(gj + 2) < W) ? p[gj + 2] : 0.f;
                    float a3 = ((unsigned)(gj + 3) < W) ? p[gj + 3] : 0.f;
                    v = make_float4(a0, a1, a2, a3);
                }
            }
            *(float4*)&su[pl][row][4 * k] = v;
        }
        __syncthreads();
    }

    auto strip1 = [&](int rr, int s, bool interior) {
        const int gi  = i0 + rr;
        const int gjb = j0 + s;
        const bool row_ok = (unsigned)gi < H;

        float yv[4], x2c[4], r0c[4], r1c[4];
        if (row_ok && gjb >= 0 && gjb + 3 < W) {
            const int p = cb + gi * W + gjb;
            *(float4*)yv = *(const float4*)(y + p);
            if (MODE != 0) {
                *(float4*)x2c = *(const float4*)(src + p);
                *(float4*)r0c = *(const float4*)(src + CHW + p);
                *(float4*)r1c = *(const float4*)(src + 2 * CHW + p);
            }
        } else {
            #pragma unroll
            for (int e = 0; e < 4; ++e) {
                const int gj = gjb + e;
                const bool ok = row_ok && ((unsigned)gj < W);
                const int p = cb + gi * W + gj;
                yv[e] = ok ? y[p] : 0.f;
                if (MODE != 0) {
                    x2c[e] = ok ? src[p] : 0.f;
                    r0c[e] = ok ? src[CHW + p] : 0.f;
                    r1c[e] = ok ? src[2 * CHW + p] : 0.f;
                }
            }
        }
        if (MODE == 0) {
            #pragma unroll
            for (int e = 0; e < 4; ++e) { x2c[e] = yv[e]; r0c[e] = 0.f; r1c[e] = 0.f; }
        }

        float t0c[4], t1c[4], t0n[4], t1w[4];
        if (MODE == 0) {
            #pragma unroll
            for (int e = 0; e < 4; ++e) { t0c[e] = t1c[e] = t0n[e] = t1w[e] = 0.f; }
        } else {
            const int lr = rr + 2;
            const int lc = s + 8;
            float4 v;
            float u0n[4], u0c[4], u0s[4], u1n[5], u1c[5], u2r[6], u3n[5], u3c[5];
            v = *(const float4*)&su[0][lr - 1][lc]; u0n[0]=v.x; u0n[1]=v.y; u0n[2]=v.z; u0n[3]=v.w;
            v = *(const float4*)&su[0][lr    ][lc]; u0c[0]=v.x; u0c[1]=v.y; u0c[2]=v.z; u0c[3]=v.w;
            v = *(const float4*)&su[0][lr + 1][lc]; u0s[0]=v.x; u0s[1]=v.y; u0s[2]=v.z; u0s[3]=v.w;
            v = *(const float4*)&su[1][lr - 1][lc]; u1n[0]=v.x; u1n[1]=v.y; u1n[2]=v.z; u1n[3]=v.w;
            u1n[4] = su[1][lr - 1][lc + 4];
            v = *(const float4*)&su[1][lr    ][lc]; u1c[0]=v.x; u1c[1]=v.y; u1c[2]=v.z; u1c[3]=v.w;
            u1c[4] = su[1][lr][lc + 4];
            u2r[0] = su[2][lr][lc - 1];
            v = *(const float4*)&su[2][lr][lc]; u2r[1]=v.x; u2r[2]=v.y; u2r[3]=v.z; u2r[4]=v.w;
            u2r[5] = su[2][lr][lc + 4];
            u3n[0] = su[3][lr - 1][lc - 1];
            v = *(const float4*)&su[3][lr - 1][lc]; u3n[1]=v.x; u3n[2]=v.y; u3n[3]=v.z; u3n[4]=v.w;
            u3c[0] = su[3][lr][lc - 1];
            v = *(const float4*)&su[3][lr][lc]; u3c[1]=v.x; u3c[2]=v.y; u3c[3]=v.z; u3c[4]=v.w;

            const bool im0 = gi > 0, imHl = gi < H - 1;
            #pragma unroll
            for (int e = 0; e < 4; ++e) {
                const int gj = gjb + e;
                const bool jm0 = gj > 0;
                t0c[e] = TAU * (u0c[e] - u0s[e] + (jm0 ? u1c[e] : 0.f) - u1c[e + 1]);
                t1c[e] = TAU * (u2r[e + 1] - u2r[e + 2] + u3n[e + 1] - (imHl ? u3c[e + 1] : 0.f));
                t0n[e] = im0 ? TAU * (u0n[e] - u0c[e] + (jm0 ? u1n[e] : 0.f) - u1n[e + 1]) : 0.f;
                t1w[e] = jm0 ? TAU * (u2r[e] - u2r[e + 1] + u3n[e] - (imHl ? u3c[e] : 0.f)) : 0.f;
            }
        }

        const bool imH = gi < H - 1;
        float xnew[4], rn0[4], rn1[4], xb[4], rb0[4], rb1[4];
        #pragma unroll
        for (int e = 0; e < 4; ++e) {
            const int gj = gjb + e;
            const bool jmW = gj < W - 1;
            const float nT  = t0n[e] - (imH ? t0c[e] : 0.f) + t1w[e] - (jmW ? t1c[e] : 0.f);
            const float xv  = (x2c[e] - nT + TAU * yv[e]) * INV_1PT;
            xb[e] = 2.f * xv - x2c[e];
            const float rp0 = r0c[e] + t0c[e];
            const float rp1 = r1c[e] + t1c[e];
            const float nrm = sqrtf(rp0 * rp0 + rp1 * rp1);
            const float f   = 1.f - 1.f / fmaxf(nrm * INV_TL1, 1.f);
            const float rv0 = rp0 * f, rv1 = rp1 * f;
            rb0[e]  = 2.f * rv0 - r0c[e];
            rb1[e]  = 2.f * rv1 - r1c[e];
            xnew[e] = x2c[e] + RHO * (xv - x2c[e]);
            rn0[e]  = r0c[e] + RHO * (rv0 - r0c[e]);
            rn1[e]  = r1c[e] + RHO * (rv1 - r1c[e]);
        }
        *(float4*)&sb[0][rr + 1][s + 4] = *(float4*)xb;
        *(float4*)&sb[1][rr + 1][s + 4] = *(float4*)rb0;
        *(float4*)&sb[2][rr + 1][s + 4] = *(float4*)rb1;

        if (interior) {
            const int p = cb + gi * W + gjb;
            if (MODE == 2) {
                *(float4*)(dst + p) = *(float4*)xnew;
                *(float4*)(dst + CHW + 2 * p)     = make_float4(rn0[0], rn1[0], rn0[1], rn1[1]);
                *(float4*)(dst + CHW + 2 * p + 4) = make_float4(rn0[2], rn1[2], rn0[3], rn1[3]);
            } else {
                *(float4*)(dst + p)           = *(float4*)xnew;
                *(float4*)(dst + CHW + p)     = *(float4*)rn0;
                *(float4*)(dst + 2 * CHW + p) = *(float4*)rn1;
            }
        }
    };

    {
        const int ty = tid >> 4, tx = tid & 15;
        strip1(ty, 4 * tx, true);
    }
    if (tid < 68) {
        int rr, s;
        if (tid < 18)      { rr = -1;       s = 4 * tid - 4; }
        else if (tid < 36) { rr = TH;       s = 4 * (tid - 18) - 4; }
        else if (tid < 52) { rr = tid - 36; s = -4; }
        else               { rr = tid - 52; s = TW; }
        strip1(rr, s, false);
    }
    __syncthreads();

    {
        const int tx = tid & 15, ty = tid >> 4;
        const int gi  = i0 + ty;
        const int gjb = j0 + 4 * tx;
        const int lr  = ty + 1;
        const int lc  = 4 * tx + 4;
        float4 v;
        float xA[6], xS[6], xN[4], r0C[5], r0N[4], r1C[5], r1S[4];
        xA[0] = sb[0][lr][lc - 1];
        v = *(const float4*)&sb[0][lr][lc]; xA[1]=v.x; xA[2]=v.y; xA[3]=v.z; xA[4]=v.w;
        xA[5] = sb[0][lr][lc + 4];
        xS[0] = sb[0][lr + 1][lc - 1];
        v = *(const float4*)&sb[0][lr + 1][lc]; xS[1]=v.x; xS[2]=v.y; xS[3]=v.z; xS[4]=v.w;
        xS[5] = sb[0][lr + 1][lc + 4];
        v = *(const float4*)&sb[0][lr - 1][lc]; xN[0]=v.x; xN[1]=v.y; xN[2]=v.z; xN[3]=v.w;
        r0C[0] = sb[1][lr][lc - 1];
        v = *(const float4*)&sb[1][lr][lc]; r0C[1]=v.x; r0C[2]=v.y; r0C[3]=v.z; r0C[4]=v.w;
        v = *(const float4*)&sb[1][lr - 1][lc]; r0N[0]=v.x; r0N[1]=v.y; r0N[2]=v.z; r0N[3]=v.w;
        r1C[0] = sb[2][lr][lc - 1];
        v = *(const float4*)&sb[2][lr][lc]; r1C[1]=v.x; r1C[2]=v.y; r1C[3]=v.z; r1C[4]=v.w;
        v = *(const float4*)&sb[2][lr + 1][lc]; r1S[0]=v.x; r1S[1]=v.y; r1S[2]=v.z; r1S[3]=v.w;

        float u0o[4], u1o[4], u2o[4], u3o[4];
        if (MODE == 0) {
            #pragma unroll
            for (int e = 0; e < 4; ++e) { u0o[e] = u1o[e] = u2o[e] = u3o[e] = 0.f; }
        } else {
            const int lru = ty + 2, lcu = 4 * tx + 8;
            v = *(const float4*)&su[0][lru][lcu]; u0o[0]=v.x; u0o[1]=v.y; u0o[2]=v.z; u0o[3]=v.w;
            v = *(const float4*)&su[1][lru][lcu]; u1o[0]=v.x; u1o[1]=v.y; u1o[2]=v.z; u1o[3]=v.w;
            v = *(const float4*)&su[2][lru][lcu]; u2o[0]=v.x; u2o[1]=v.y; u2o[2]=v.z; u2o[3]=v.w;
            v = *(const float4*)&su[3][lru][lcu]; u3o[0]=v.x; u3o[1]=v.y; u3o[2]=v.z; u3o[3]=v.w;
        }

        const bool im0 = gi > 0, imH = gi < H - 1;
        float un0[4], un1[4], un2[4], un3[4];
        #pragma unroll
        for (int e = 0; e < 4; ++e) {
            const int gj = gjb + e;
            const bool jm0 = gj > 0, jmW = gj < W - 1;
            const float xC = xA[e + 1], xE = xA[e + 2], xW_ = xA[e];
            const float I0c = (imH ? xS[e + 1] - xC : 0.f) - r0C[e + 1];
            const float I0n = im0 ? (xC - xN[e] - r0N[e]) : 0.f;
            const float I0w = jm0 ? ((imH ? xS[e] - xW_ : 0.f) - r0C[e]) : 0.f;
            const float I1c = (jmW ? xE - xC : 0.f) - r1C[e + 1];
            const float I1w = jm0 ? (xC - xW_ - r1C[e]) : 0.f;
            const float I1s = imH ? ((jmW ? xS[e + 2] - xS[e + 1] : 0.f) - r1S[e]) : 0.f;
            const float g0 = I0c - I0n;
            const float g1 = jm0 ? (I0c - I0w) : 0.f;
            const float g2 = I1c - I1w;
            const float g3 = imH ? (I1s - I1c) : 0.f;
            const float up0 = u0o[e] + SIGMA * g0;
            const float up1 = u1o[e] + SIGMA * g1;
            const float up2 = u2o[e] + SIGMA * g2;
            const float up3 = u3o[e] + SIGMA * g3;
            const float nrm = sqrtf(up0 * up0 + up1 * up1 + up2 * up2 + up3 * up3);
            const float inv = 1.f / fmaxf(nrm * (1.0f / LAM2), 1.f);
            un0[e] = u0o[e] + RHO * (up0 * inv - u0o[e]);
            un1[e] = u1o[e] + RHO * (up1 * inv - u1o[e]);
            un2[e] = u2o[e] + RHO * (up2 * inv - u2o[e]);
            un3[e] = u3o[e] + RHO * (up3 * inv - u3o[e]);
        }
        const int p = cb + gi * W + gjb;
        if (MODE == 2) {
            #pragma unroll
            for (int e = 0; e < 4; ++e)
                *(float4*)(dst + 3 * CHW + 4 * (p + e)) =
                    make_float4(un0[e], un1[e], un2[e], un3[e]);
        } else {
            *(float4*)(dst + 3 * CHW + p) = *(float4*)un0;
            *(float4*)(dst + 4 * CHW + p) = *(float4*)un1;
            *(float4*)(dst + 5 * CHW + p) = *(float4*)un2;
            *(float4*)(dst + 6 * CHW + p) = *(float4*)un3;
        }
    }
}

extern "C" void kernel_launch(void* const* d_in, const int* in_sizes, int n_in,
                              void* d_out, int out_size, void* d_ws, size_t ws_size,
                              hipStream_t stream) {
    const float* y = (const float*)d_in[0];
    float* out = (float*)d_out;
    float* b0  = (float*)d_ws;
    float* b1  = b0 + 7 * CHW;      // 2 x 7 planes = 44 MB, ws is ~256 MB

    dim3 blk(256, 1, 1);
    dim3 grd(W / TW, H / TH, C);    // (8, 32, 3) = 768 blocks = exactly 3/CU

    void* args[] = { (void*)&y, (void*)&b0, (void*)&b1, (void*)&out };
    hipError_t err = hipLaunchCooperativeKernel((const void*)tgv_all, grd, blk,
                                                args, 0u, stream);
    if (err != hipSuccess) {
        // cooperative launch unsupported here -> verified multi-launch path
        fused_it<0><<<grd, blk, 0, stream>>>(y, b0 /*unused*/, b0);
        for (int k = 2; k < N_IT; ++k) {
            float* s = (k % 2 == 0) ? b0 : b1;
            float* d = (k % 2 == 0) ? b1 : b0;
            fused_it<1><<<grd, blk, 0, stream>>>(y, s, d);
        }
        fused_it<2><<<grd, blk, 0, stream>>>(y, b0, out);
    }
}

// Round 4
// 418.987 us; speedup vs baseline: 14.3499x; 14.3499x over previous
//
#include <hip/hip_runtime.h>

// TGV prox primal-dual, 30 iterations on (3,512,512) fp32.
// Multi-launch structure (verified 434.6us baseline) + fp16 compression of the
// r/u state planes (x2 stays fp32; y, all arithmetic, and final output fp32).
//  - ping-pong state per buffer: x2 plane fp32 (CHW floats) + 6 fp16 planes
//    (r0, r1, u0..u3; 6*CHW halves). Traffic 45.5 -> 27.6 MB/iter.
//  - u planes staged to LDS as FLOAT (converted during staging), so stage-1/
//    stage-2 LDS access patterns are unchanged from the verified kernel.
//  - precision: u is ball-projected to radius 0.15 (fp16 ulp ~6e-5, enters x
//    through tau=0.01); r is ~6e-3 magnitude. x2 is O(1) -> kept fp32.
// R3 post-mortem: persistent cooperative kernel was correct but grid.sync +
// device fences cost ~200us/iter on 8 XCDs (VALUBusy 2.3%) -> a kernel launch
// is the cheapest grid barrier on this chip. Do not revisit.

#define H 512
#define W 512
#define C 3
#define HW (H * W)
#define CHW (C * H * W)
#define N_IT 30

#define TW 64
#define TH 16

#define TAU     0.01f
#define LAM2    0.15f
#define RHO     1.99f
#define SIGMA   1.3888888888888888f   /* 1/TAU/72 */
#define INV_TL1 1000.0f               /* 1/(TAU*LAM1) */
#define INV_1PT (1.0f / 1.01f)        /* 1/(1+TAU) */

// u planes rows i0-2..i0+17 (20), cols j0-8..j0+67 (19 float4 chunks, lc=gj-j0+8)
#define UROWS 20
#define USTR  80
// xbar/rbar planes rows -1..16 (18), cols lc = col+4 (col -4..67)
#define BROWS 18
#define BSTR  72

typedef _Float16 f16;
typedef __attribute__((ext_vector_type(4))) _Float16 h4;

// fp16 state plane order within an h-buffer: 0=r0 1=r1 2..5=u0..u3
#define HP_R0 0
#define HP_R1 1
#define HP_U  2

template <int MODE> // 0 = first iter, 1 = middle, 2 = last (dst = d_out interleaved)
__global__ __launch_bounds__(256)
void fused_it(const float* __restrict__ y,
              const float* __restrict__ srcX,
              const f16*   __restrict__ srcH,
              float*       __restrict__ dstX,
              f16*         __restrict__ dstH,
              float*       __restrict__ outp)
{
    __shared__ float su[4][UROWS][USTR];
    __shared__ float sb[3][BROWS][BSTR]; // 0=xbar 1=rbar0 2=rbar1

    const int tid = threadIdx.x;
    const int c   = blockIdx.z;
    const int i0  = blockIdx.y * TH;
    const int j0  = blockIdx.x * TW;
    const int cb  = c * HW;

    // ---- stage u planes (fp16 in global) into LDS as float ----
    if (MODE != 0) {
        for (int t = tid; t < 4 * UROWS * 19; t += 256) {
            const int pl  = t / (UROWS * 19);
            const int rm  = t - pl * (UROWS * 19);
            const int row = rm / 19;
            const int k   = rm - row * 19;
            const int gi  = i0 + row - 2;
            const int gj  = j0 + 4 * k - 8;
            float4 v = make_float4(0.f, 0.f, 0.f, 0.f);
            if ((unsigned)gi < H) {
                const f16* p = srcH + (HP_U + pl) * CHW + cb + gi * W;
                if (gj >= 0 && gj + 3 < W) {
                    h4 hv = *(const h4*)(p + gj);
                    v = make_float4((float)hv[0], (float)hv[1], (float)hv[2], (float)hv[3]);
                } else {
                    float a0 = ((unsigned)(gj + 0) < W) ? (float)p[gj + 0] : 0.f;
                    float a1 = ((unsigned)(gj + 1) < W) ? (float)p[gj + 1] : 0.f;
                    float a2 = ((unsigned)(gj + 2) < W) ? (float)p[gj + 2] : 0.f;
                    float a3 = ((unsigned)(gj + 3) < W) ? (float)p[gj + 3] : 0.f;
                    v = make_float4(a0, a1, a2, a3);
                }
            }
            *(float4*)&su[pl][row][4 * k] = v;
        }
        __syncthreads();
    }

    // ---- stage 1: x/r prox on a strip of 4 positions; xbar/rbar -> LDS ----
    auto strip1 = [&](int rr, int s, bool interior) {
        const int gi  = i0 + rr;
        const int gjb = j0 + s;
        const bool row_ok = (unsigned)gi < H;

        float yv[4], x2c[4], r0c[4], r1c[4];
        if (row_ok && gjb >= 0 && gjb + 3 < W) {
            const int p = cb + gi * W + gjb;
            *(float4*)yv = *(const float4*)(y + p);
            if (MODE != 0) {
                *(float4*)x2c = *(const float4*)(srcX + p);
                h4 h0 = *(const h4*)(srcH + HP_R0 * CHW + p);
                h4 h1 = *(const h4*)(srcH + HP_R1 * CHW + p);
                #pragma unroll
                for (int e = 0; e < 4; ++e) { r0c[e] = (float)h0[e]; r1c[e] = (float)h1[e]; }
            }
        } else {
            #pragma unroll
            for (int e = 0; e < 4; ++e) {
                const int gj = gjb + e;
                const bool ok = row_ok && ((unsigned)gj < W);
                const int p = cb + gi * W + gj;
                yv[e] = ok ? y[p] : 0.f;
                if (MODE != 0) {
                    x2c[e] = ok ? srcX[p] : 0.f;
                    r0c[e] = ok ? (float)srcH[HP_R0 * CHW + p] : 0.f;
                    r1c[e] = ok ? (float)srcH[HP_R1 * CHW + p] : 0.f;
                }
            }
        }
        if (MODE == 0) {
            #pragma unroll
            for (int e = 0; e < 4; ++e) { x2c[e] = yv[e]; r0c[e] = 0.f; r1c[e] = 0.f; }
        }

        float t0c[4], t1c[4], t0n[4], t1w[4];
        if (MODE == 0) {
            #pragma unroll
            for (int e = 0; e < 4; ++e) { t0c[e] = t1c[e] = t0n[e] = t1w[e] = 0.f; }
        } else {
            const int lr = rr + 2;
            const int lc = s + 8;
            float4 v;
            float u0n[4], u0c[4], u0s[4], u1n[5], u1c[5], u2r[6], u3n[5], u3c[5];
            v = *(const float4*)&su[0][lr - 1][lc]; u0n[0]=v.x; u0n[1]=v.y; u0n[2]=v.z; u0n[3]=v.w;
            v = *(const float4*)&su[0][lr    ][lc]; u0c[0]=v.x; u0c[1]=v.y; u0c[2]=v.z; u0c[3]=v.w;
            v = *(const float4*)&su[0][lr + 1][lc]; u0s[0]=v.x; u0s[1]=v.y; u0s[2]=v.z; u0s[3]=v.w;
            v = *(const float4*)&su[1][lr - 1][lc]; u1n[0]=v.x; u1n[1]=v.y; u1n[2]=v.z; u1n[3]=v.w;
            u1n[4] = su[1][lr - 1][lc + 4];
            v = *(const float4*)&su[1][lr    ][lc]; u1c[0]=v.x; u1c[1]=v.y; u1c[2]=v.z; u1c[3]=v.w;
            u1c[4] = su[1][lr][lc + 4];
            u2r[0] = su[2][lr][lc - 1];
            v = *(const float4*)&su[2][lr][lc]; u2r[1]=v.x; u2r[2]=v.y; u2r[3]=v.z; u2r[4]=v.w;
            u2r[5] = su[2][lr][lc + 4];
            u3n[0] = su[3][lr - 1][lc - 1];
            v = *(const float4*)&su[3][lr - 1][lc]; u3n[1]=v.x; u3n[2]=v.y; u3n[3]=v.z; u3n[4]=v.w;
            u3c[0] = su[3][lr][lc - 1];
            v = *(const float4*)&su[3][lr][lc]; u3c[1]=v.x; u3c[2]=v.y; u3c[3]=v.z; u3c[4]=v.w;

            const bool im0 = gi > 0, imHl = gi < H - 1;
            #pragma unroll
            for (int e = 0; e < 4; ++e) {
                const int gj = gjb + e;
                const bool jm0 = gj > 0;
                t0c[e] = TAU * (u0c[e] - u0s[e] + (jm0 ? u1c[e] : 0.f) - u1c[e + 1]);
                t1c[e] = TAU * (u2r[e + 1] - u2r[e + 2] + u3n[e + 1] - (imHl ? u3c[e + 1] : 0.f));
                t0n[e] = im0 ? TAU * (u0n[e] - u0c[e] + (jm0 ? u1n[e] : 0.f) - u1n[e + 1]) : 0.f;
                t1w[e] = jm0 ? TAU * (u2r[e] - u2r[e + 1] + u3n[e] - (imHl ? u3c[e] : 0.f)) : 0.f;
            }
        }

        const bool imH = gi < H - 1;
        float xnew[4], rn0[4], rn1[4], xb[4], rb0[4], rb1[4];
        #pragma unroll
        for (int e = 0; e < 4; ++e) {
            const int gj = gjb + e;
            const bool jmW = gj < W - 1;
            const float nT  = t0n[e] - (imH ? t0c[e] : 0.f) + t1w[e] - (jmW ? t1c[e] : 0.f);
            const float xv  = (x2c[e] - nT + TAU * yv[e]) * INV_1PT;
            xb[e] = 2.f * xv - x2c[e];
            const float rp0 = r0c[e] + t0c[e];
            const float rp1 = r1c[e] + t1c[e];
            const float nrm = sqrtf(rp0 * rp0 + rp1 * rp1);
            const float f   = 1.f - 1.f / fmaxf(nrm * INV_TL1, 1.f);
            const float rv0 = rp0 * f, rv1 = rp1 * f;
            rb0[e]  = 2.f * rv0 - r0c[e];
            rb1[e]  = 2.f * rv1 - r1c[e];
            xnew[e] = x2c[e] + RHO * (xv - x2c[e]);
            rn0[e]  = r0c[e] + RHO * (rv0 - r0c[e]);
            rn1[e]  = r1c[e] + RHO * (rv1 - r1c[e]);
        }
        *(float4*)&sb[0][rr + 1][s + 4] = *(float4*)xb;
        *(float4*)&sb[1][rr + 1][s + 4] = *(float4*)rb0;
        *(float4*)&sb[2][rr + 1][s + 4] = *(float4*)rb1;

        if (interior) {
            const int p = cb + gi * W + gjb;
            if (MODE == 2) {
                *(float4*)(outp + p) = *(float4*)xnew;
                *(float4*)(outp + CHW + 2 * p)     = make_float4(rn0[0], rn1[0], rn0[1], rn1[1]);
                *(float4*)(outp + CHW + 2 * p + 4) = make_float4(rn0[2], rn1[2], rn0[3], rn1[3]);
            } else {
                *(float4*)(dstX + p) = *(float4*)xnew;
                h4 h0, h1;
                #pragma unroll
                for (int e = 0; e < 4; ++e) { h0[e] = (f16)rn0[e]; h1[e] = (f16)rn1[e]; }
                *(h4*)(dstH + HP_R0 * CHW + p) = h0;
                *(h4*)(dstH + HP_R1 * CHW + p) = h1;
            }
        }
    };

    { // pass 1: interior 16 rows x 16 strips
        const int ty = tid >> 4, tx = tid & 15;
        strip1(ty, 4 * tx, true);
    }
    if (tid < 68) { // pass 2: +1 ring strips
        int rr, s;
        if (tid < 18)      { rr = -1;       s = 4 * tid - 4; }
        else if (tid < 36) { rr = TH;       s = 4 * (tid - 18) - 4; }
        else if (tid < 52) { rr = tid - 36; s = -4; }
        else               { rr = tid - 52; s = TW; }
        strip1(rr, s, false);
    }
    __syncthreads();

    // ---- stage 2: u prox on interior, xbar/rbar from LDS ----
    {
        const int tx = tid & 15, ty = tid >> 4;
        const int gi  = i0 + ty;
        const int gjb = j0 + 4 * tx;
        const int lr  = ty + 1;
        const int lc  = 4 * tx + 4;
        float4 v;
        float xA[6], xS[6], xN[4], r0C[5], r0N[4], r1C[5], r1S[4];
        xA[0] = sb[0][lr][lc - 1];
        v = *(const float4*)&sb[0][lr][lc]; xA[1]=v.x; xA[2]=v.y; xA[3]=v.z; xA[4]=v.w;
        xA[5] = sb[0][lr][lc + 4];
        xS[0] = sb[0][lr + 1][lc - 1];
        v = *(const float4*)&sb[0][lr + 1][lc]; xS[1]=v.x; xS[2]=v.y; xS[3]=v.z; xS[4]=v.w;
        xS[5] = sb[0][lr + 1][lc + 4];
        v = *(const float4*)&sb[0][lr - 1][lc]; xN[0]=v.x; xN[1]=v.y; xN[2]=v.z; xN[3]=v.w;
        r0C[0] = sb[1][lr][lc - 1];
        v = *(const float4*)&sb[1][lr][lc]; r0C[1]=v.x; r0C[2]=v.y; r0C[3]=v.z; r0C[4]=v.w;
        v = *(const float4*)&sb[1][lr - 1][lc]; r0N[0]=v.x; r0N[1]=v.y; r0N[2]=v.z; r0N[3]=v.w;
        r1C[0] = sb[2][lr][lc - 1];
        v = *(const float4*)&sb[2][lr][lc]; r1C[1]=v.x; r1C[2]=v.y; r1C[3]=v.z; r1C[4]=v.w;
        v = *(const float4*)&sb[2][lr + 1][lc]; r1S[0]=v.x; r1S[1]=v.y; r1S[2]=v.z; r1S[3]=v.w;

        float u0o[4], u1o[4], u2o[4], u3o[4];
        if (MODE == 0) {
            #pragma unroll
            for (int e = 0; e < 4; ++e) { u0o[e] = u1o[e] = u2o[e] = u3o[e] = 0.f; }
        } else {
            const int lru = ty + 2, lcu = 4 * tx + 8;
            v = *(const float4*)&su[0][lru][lcu]; u0o[0]=v.x; u0o[1]=v.y; u0o[2]=v.z; u0o[3]=v.w;
            v = *(const float4*)&su[1][lru][lcu]; u1o[0]=v.x; u1o[1]=v.y; u1o[2]=v.z; u1o[3]=v.w;
            v = *(const float4*)&su[2][lru][lcu]; u2o[0]=v.x; u2o[1]=v.y; u2o[2]=v.z; u2o[3]=v.w;
            v = *(const float4*)&su[3][lru][lcu]; u3o[0]=v.x; u3o[1]=v.y; u3o[2]=v.z; u3o[3]=v.w;
        }

        const bool im0 = gi > 0, imH = gi < H - 1;
        float un0[4], un1[4], un2[4], un3[4];
        #pragma unroll
        for (int e = 0; e < 4; ++e) {
            const int gj = gjb + e;
            const bool jm0 = gj > 0, jmW = gj < W - 1;
            const float xC = xA[e + 1], xE = xA[e + 2], xW_ = xA[e];
            const float I0c = (imH ? xS[e + 1] - xC : 0.f) - r0C[e + 1];
            const float I0n = im0 ? (xC - xN[e] - r0N[e]) : 0.f;
            const float I0w = jm0 ? ((imH ? xS[e] - xW_ : 0.f) - r0C[e]) : 0.f;
            const float I1c = (jmW ? xE - xC : 0.f) - r1C[e + 1];
            const float I1w = jm0 ? (xC - xW_ - r1C[e]) : 0.f;
            const float I1s = imH ? ((jmW ? xS[e + 2] - xS[e + 1] : 0.f) - r1S[e]) : 0.f;
            const float g0 = I0c - I0n;
            const float g1 = jm0 ? (I0c - I0w) : 0.f;
            const float g2 = I1c - I1w;
            const float g3 = imH ? (I1s - I1c) : 0.f;
            const float up0 = u0o[e] + SIGMA * g0;
            const float up1 = u1o[e] + SIGMA * g1;
            const float up2 = u2o[e] + SIGMA * g2;
            const float up3 = u3o[e] + SIGMA * g3;
            const float nrm = sqrtf(up0 * up0 + up1 * up1 + up2 * up2 + up3 * up3);
            const float inv = 1.f / fmaxf(nrm * (1.0f / LAM2), 1.f);
            un0[e] = u0o[e] + RHO * (up0 * inv - u0o[e]);
            un1[e] = u1o[e] + RHO * (up1 * inv - u1o[e]);
            un2[e] = u2o[e] + RHO * (up2 * inv - u2o[e]);
            un3[e] = u3o[e] + RHO * (up3 * inv - u3o[e]);
        }
        const int p = cb + gi * W + gjb;
        if (MODE == 2) {
            #pragma unroll
            for (int e = 0; e < 4; ++e)
                *(float4*)(outp + 3 * CHW + 4 * (p + e)) =
                    make_float4(un0[e], un1[e], un2[e], un3[e]);
        } else {
            h4 o0, o1, o2, o3;
            #pragma unroll
            for (int e = 0; e < 4; ++e) {
                o0[e] = (f16)un0[e]; o1[e] = (f16)un1[e];
                o2[e] = (f16)un2[e]; o3[e] = (f16)un3[e];
            }
            *(h4*)(dstH + (HP_U + 0) * CHW + p) = o0;
            *(h4*)(dstH + (HP_U + 1) * CHW + p) = o1;
            *(h4*)(dstH + (HP_U + 2) * CHW + p) = o2;
            *(h4*)(dstH + (HP_U + 3) * CHW + p) = o3;
        }
    }
}

extern "C" void kernel_launch(void* const* d_in, const int* in_sizes, int n_in,
                              void* d_out, int out_size, void* d_ws, size_t ws_size,
                              hipStream_t stream) {
    const float* y = (const float*)d_in[0];
    float* out = (float*)d_out;

    // ws layout: x2 fp32 buf0 | x2 fp32 buf1 | h-buf0 (6*CHW f16) | h-buf1
    float* x0 = (float*)d_ws;
    float* x1 = x0 + CHW;
    f16*   h0 = (f16*)(x1 + CHW);
    f16*   h1 = h0 + 6 * CHW;

    dim3 blk(256, 1, 1);
    dim3 grd(W / TW, H / TH, C);    // (8, 32, 3) = 768 blocks = 3/CU

    fused_it<0><<<grd, blk, 0, stream>>>(y, nullptr, nullptr, x0, h0, nullptr);
    for (int k = 2; k < N_IT; ++k) {
        const bool even = (k % 2 == 0);
        float* sx = even ? x0 : x1;  f16* sh = even ? h0 : h1;
        float* dx = even ? x1 : x0;  f16* dh = even ? h1 : h0;
        fused_it<1><<<grd, blk, 0, stream>>>(y, sx, sh, dx, dh, nullptr);
    }
    fused_it<2><<<grd, blk, 0, stream>>>(y, x0, h0, nullptr, nullptr, out);
}

// Round 5
// 405.826 us; speedup vs baseline: 14.8153x; 1.0324x over previous
//
#include <hip/hip_runtime.h>

// TGV prox primal-dual, 30 iterations on (3,512,512) fp32.
// Multi-launch structure + fp16 r/u state (verified 419us). This revision:
// TH 16->8 retile for latency hiding:
//  - LDS 41.1 -> 24.0 KB => 6 blocks/CU resident (was 3); grid (8,64,3)=1536
//    blocks = exactly one 6/CU round. Doubles cross-block phase overlap.
//  - interior = 128 strips -> threads 0-127; the 52 ring strips run on
//    threads 128-179 CONCURRENTLY (different waves) instead of serially
//    after pass 1 (removes exposed ring-load latency from critical path).
// R3 post-mortem: persistent cooperative kernel correct but grid.sync costs
// ~200us/iter on 8 XCDs -> launch IS the cheapest grid barrier. Don't revisit.
// R4 post-mortem: 1.65x traffic cut gained only 3.6% -> NOT BW-bound;
// latency/TLP-bound. This round attacks TLP.

#define H 512
#define W 512
#define C 3
#define HW (H * W)
#define CHW (C * H * W)
#define N_IT 30

#define TW 64
#define TH 8

#define TAU     0.01f
#define LAM2    0.15f
#define RHO     1.99f
#define SIGMA   1.3888888888888888f   /* 1/TAU/72 */
#define INV_TL1 1000.0f               /* 1/(TAU*LAM1) */
#define INV_1PT (1.0f / 1.01f)        /* 1/(1+TAU) */

// u planes rows i0-2..i0+9 (12), cols j0-8..j0+67 (19 float4 chunks, lc=gj-j0+8)
#define UROWS 12
#define USTR  80
// xbar/rbar planes rows -1..8 (10), cols lc = col+4 (col -4..67)
#define BROWS 10
#define BSTR  72

typedef _Float16 f16;
typedef __attribute__((ext_vector_type(4))) _Float16 h4;

// fp16 state plane order within an h-buffer: 0=r0 1=r1 2..5=u0..u3
#define HP_R0 0
#define HP_R1 1
#define HP_U  2

template <int MODE> // 0 = first iter, 1 = middle, 2 = last (dst = d_out interleaved)
__global__ __launch_bounds__(256)
void fused_it(const float* __restrict__ y,
              const float* __restrict__ srcX,
              const f16*   __restrict__ srcH,
              float*       __restrict__ dstX,
              f16*         __restrict__ dstH,
              float*       __restrict__ outp)
{
    __shared__ float su[4][UROWS][USTR];
    __shared__ float sb[3][BROWS][BSTR]; // 0=xbar 1=rbar0 2=rbar1

    const int tid = threadIdx.x;
    const int c   = blockIdx.z;
    const int i0  = blockIdx.y * TH;
    const int j0  = blockIdx.x * TW;
    const int cb  = c * HW;

    // ---- stage u planes (fp16 in global) into LDS as float ----
    if (MODE != 0) {
        for (int t = tid; t < 4 * UROWS * 19; t += 256) {
            const int pl  = t / (UROWS * 19);
            const int rm  = t - pl * (UROWS * 19);
            const int row = rm / 19;
            const int k   = rm - row * 19;
            const int gi  = i0 + row - 2;
            const int gj  = j0 + 4 * k - 8;
            float4 v = make_float4(0.f, 0.f, 0.f, 0.f);
            if ((unsigned)gi < H) {
                const f16* p = srcH + (HP_U + pl) * CHW + cb + gi * W;
                if (gj >= 0 && gj + 3 < W) {
                    h4 hv = *(const h4*)(p + gj);
                    v = make_float4((float)hv[0], (float)hv[1], (float)hv[2], (float)hv[3]);
                } else {
                    float a0 = ((unsigned)(gj + 0) < W) ? (float)p[gj + 0] : 0.f;
                    float a1 = ((unsigned)(gj + 1) < W) ? (float)p[gj + 1] : 0.f;
                    float a2 = ((unsigned)(gj + 2) < W) ? (float)p[gj + 2] : 0.f;
                    float a3 = ((unsigned)(gj + 3) < W) ? (float)p[gj + 3] : 0.f;
                    v = make_float4(a0, a1, a2, a3);
                }
            }
            *(float4*)&su[pl][row][4 * k] = v;
        }
        __syncthreads();
    }

    // ---- stage 1: x/r prox on a strip of 4 positions; xbar/rbar -> LDS ----
    auto strip1 = [&](int rr, int s, bool interior) {
        const int gi  = i0 + rr;
        const int gjb = j0 + s;
        const bool row_ok = (unsigned)gi < H;

        float yv[4], x2c[4], r0c[4], r1c[4];
        if (row_ok && gjb >= 0 && gjb + 3 < W) {
            const int p = cb + gi * W + gjb;
            *(float4*)yv = *(const float4*)(y + p);
            if (MODE != 0) {
                *(float4*)x2c = *(const float4*)(srcX + p);
                h4 h0 = *(const h4*)(srcH + HP_R0 * CHW + p);
                h4 h1 = *(const h4*)(srcH + HP_R1 * CHW + p);
                #pragma unroll
                for (int e = 0; e < 4; ++e) { r0c[e] = (float)h0[e]; r1c[e] = (float)h1[e]; }
            }
        } else {
            #pragma unroll
            for (int e = 0; e < 4; ++e) {
                const int gj = gjb + e;
                const bool ok = row_ok && ((unsigned)gj < W);
                const int p = cb + gi * W + gj;
                yv[e] = ok ? y[p] : 0.f;
                if (MODE != 0) {
                    x2c[e] = ok ? srcX[p] : 0.f;
                    r0c[e] = ok ? (float)srcH[HP_R0 * CHW + p] : 0.f;
                    r1c[e] = ok ? (float)srcH[HP_R1 * CHW + p] : 0.f;
                }
            }
        }
        if (MODE == 0) {
            #pragma unroll
            for (int e = 0; e < 4; ++e) { x2c[e] = yv[e]; r0c[e] = 0.f; r1c[e] = 0.f; }
        }

        float t0c[4], t1c[4], t0n[4], t1w[4];
        if (MODE == 0) {
            #pragma unroll
            for (int e = 0; e < 4; ++e) { t0c[e] = t1c[e] = t0n[e] = t1w[e] = 0.f; }
        } else {
            const int lr = rr + 2;
            const int lc = s + 8;
            float4 v;
            float u0n[4], u0c[4], u0s[4], u1n[5], u1c[5], u2r[6], u3n[5], u3c[5];
            v = *(const float4*)&su[0][lr - 1][lc]; u0n[0]=v.x; u0n[1]=v.y; u0n[2]=v.z; u0n[3]=v.w;
            v = *(const float4*)&su[0][lr    ][lc]; u0c[0]=v.x; u0c[1]=v.y; u0c[2]=v.z; u0c[3]=v.w;
            v = *(const float4*)&su[0][lr + 1][lc]; u0s[0]=v.x; u0s[1]=v.y; u0s[2]=v.z; u0s[3]=v.w;
            v = *(const float4*)&su[1][lr - 1][lc]; u1n[0]=v.x; u1n[1]=v.y; u1n[2]=v.z; u1n[3]=v.w;
            u1n[4] = su[1][lr - 1][lc + 4];
            v = *(const float4*)&su[1][lr    ][lc]; u1c[0]=v.x; u1c[1]=v.y; u1c[2]=v.z; u1c[3]=v.w;
            u1c[4] = su[1][lr][lc + 4];
            u2r[0] = su[2][lr][lc - 1];
            v = *(const float4*)&su[2][lr][lc]; u2r[1]=v.x; u2r[2]=v.y; u2r[3]=v.z; u2r[4]=v.w;
            u2r[5] = su[2][lr][lc + 4];
            u3n[0] = su[3][lr - 1][lc - 1];
            v = *(const float4*)&su[3][lr - 1][lc]; u3n[1]=v.x; u3n[2]=v.y; u3n[3]=v.z; u3n[4]=v.w;
            u3c[0] = su[3][lr][lc - 1];
            v = *(const float4*)&su[3][lr][lc]; u3c[1]=v.x; u3c[2]=v.y; u3c[3]=v.z; u3c[4]=v.w;

            const bool im0 = gi > 0, imHl = gi < H - 1;
            #pragma unroll
            for (int e = 0; e < 4; ++e) {
                const int gj = gjb + e;
                const bool jm0 = gj > 0;
                t0c[e] = TAU * (u0c[e] - u0s[e] + (jm0 ? u1c[e] : 0.f) - u1c[e + 1]);
                t1c[e] = TAU * (u2r[e + 1] - u2r[e + 2] + u3n[e + 1] - (imHl ? u3c[e + 1] : 0.f));
                t0n[e] = im0 ? TAU * (u0n[e] - u0c[e] + (jm0 ? u1n[e] : 0.f) - u1n[e + 1]) : 0.f;
                t1w[e] = jm0 ? TAU * (u2r[e] - u2r[e + 1] + u3n[e] - (imHl ? u3c[e] : 0.f)) : 0.f;
            }
        }

        const bool imH = gi < H - 1;
        float xnew[4], rn0[4], rn1[4], xb[4], rb0[4], rb1[4];
        #pragma unroll
        for (int e = 0; e < 4; ++e) {
            const int gj = gjb + e;
            const bool jmW = gj < W - 1;
            const float nT  = t0n[e] - (imH ? t0c[e] : 0.f) + t1w[e] - (jmW ? t1c[e] : 0.f);
            const float xv  = (x2c[e] - nT + TAU * yv[e]) * INV_1PT;
            xb[e] = 2.f * xv - x2c[e];
            const float rp0 = r0c[e] + t0c[e];
            const float rp1 = r1c[e] + t1c[e];
            const float nrm = sqrtf(rp0 * rp0 + rp1 * rp1);
            const float f   = 1.f - 1.f / fmaxf(nrm * INV_TL1, 1.f);
            const float rv0 = rp0 * f, rv1 = rp1 * f;
            rb0[e]  = 2.f * rv0 - r0c[e];
            rb1[e]  = 2.f * rv1 - r1c[e];
            xnew[e] = x2c[e] + RHO * (xv - x2c[e]);
            rn0[e]  = r0c[e] + RHO * (rv0 - r0c[e]);
            rn1[e]  = r1c[e] + RHO * (rv1 - r1c[e]);
        }
        *(float4*)&sb[0][rr + 1][s + 4] = *(float4*)xb;
        *(float4*)&sb[1][rr + 1][s + 4] = *(float4*)rb0;
        *(float4*)&sb[2][rr + 1][s + 4] = *(float4*)rb1;

        if (interior) {
            const int p = cb + gi * W + gjb;
            if (MODE == 2) {
                *(float4*)(outp + p) = *(float4*)xnew;
                *(float4*)(outp + CHW + 2 * p)     = make_float4(rn0[0], rn1[0], rn0[1], rn1[1]);
                *(float4*)(outp + CHW + 2 * p + 4) = make_float4(rn0[2], rn1[2], rn0[3], rn1[3]);
            } else {
                *(float4*)(dstX + p) = *(float4*)xnew;
                h4 h0, h1;
                #pragma unroll
                for (int e = 0; e < 4; ++e) { h0[e] = (f16)rn0[e]; h1[e] = (f16)rn1[e]; }
                *(h4*)(dstH + HP_R0 * CHW + p) = h0;
                *(h4*)(dstH + HP_R1 * CHW + p) = h1;
            }
        }
    };

    // stage 1, all concurrent: threads 0-127 interior (8 rows x 16 strips),
    // threads 128-179 the 52 ring strips (different waves -> true overlap)
    if (tid < 128) {
        strip1(tid >> 4, 4 * (tid & 15), true);
    } else if (tid < 180) {
        const int t = tid - 128;
        int rr, s;
        if (t < 18)      { rr = -1;      s = 4 * t - 4; }
        else if (t < 36) { rr = TH;      s = 4 * (t - 18) - 4; }
        else if (t < 44) { rr = t - 36;  s = -4; }
        else             { rr = t - 44;  s = TW; }
        strip1(rr, s, false);
    }
    __syncthreads();

    // ---- stage 2: u prox on interior, xbar/rbar from LDS ----
    if (tid < 128) {
        const int tx = tid & 15, ty = tid >> 4;
        const int gi  = i0 + ty;
        const int gjb = j0 + 4 * tx;
        const int lr  = ty + 1;
        const int lc  = 4 * tx + 4;
        float4 v;
        float xA[6], xS[6], xN[4], r0C[5], r0N[4], r1C[5], r1S[4];
        xA[0] = sb[0][lr][lc - 1];
        v = *(const float4*)&sb[0][lr][lc]; xA[1]=v.x; xA[2]=v.y; xA[3]=v.z; xA[4]=v.w;
        xA[5] = sb[0][lr][lc + 4];
        xS[0] = sb[0][lr + 1][lc - 1];
        v = *(const float4*)&sb[0][lr + 1][lc]; xS[1]=v.x; xS[2]=v.y; xS[3]=v.z; xS[4]=v.w;
        xS[5] = sb[0][lr + 1][lc + 4];
        v = *(const float4*)&sb[0][lr - 1][lc]; xN[0]=v.x; xN[1]=v.y; xN[2]=v.z; xN[3]=v.w;
        r0C[0] = sb[1][lr][lc - 1];
        v = *(const float4*)&sb[1][lr][lc]; r0C[1]=v.x; r0C[2]=v.y; r0C[3]=v.z; r0C[4]=v.w;
        v = *(const float4*)&sb[1][lr - 1][lc]; r0N[0]=v.x; r0N[1]=v.y; r0N[2]=v.z; r0N[3]=v.w;
        r1C[0] = sb[2][lr][lc - 1];
        v = *(const float4*)&sb[2][lr][lc]; r1C[1]=v.x; r1C[2]=v.y; r1C[3]=v.z; r1C[4]=v.w;
        v = *(const float4*)&sb[2][lr + 1][lc]; r1S[0]=v.x; r1S[1]=v.y; r1S[2]=v.z; r1S[3]=v.w;

        float u0o[4], u1o[4], u2o[4], u3o[4];
        if (MODE == 0) {
            #pragma unroll
            for (int e = 0; e < 4; ++e) { u0o[e] = u1o[e] = u2o[e] = u3o[e] = 0.f; }
        } else {
            const int lru = ty + 2, lcu = 4 * tx + 8;
            v = *(const float4*)&su[0][lru][lcu]; u0o[0]=v.x; u0o[1]=v.y; u0o[2]=v.z; u0o[3]=v.w;
            v = *(const float4*)&su[1][lru][lcu]; u1o[0]=v.x; u1o[1]=v.y; u1o[2]=v.z; u1o[3]=v.w;
            v = *(const float4*)&su[2][lru][lcu]; u2o[0]=v.x; u2o[1]=v.y; u2o[2]=v.z; u2o[3]=v.w;
            v = *(const float4*)&su[3][lru][lcu]; u3o[0]=v.x; u3o[1]=v.y; u3o[2]=v.z; u3o[3]=v.w;
        }

        const bool im0 = gi > 0, imH = gi < H - 1;
        float un0[4], un1[4], un2[4], un3[4];
        #pragma unroll
        for (int e = 0; e < 4; ++e) {
            const int gj = gjb + e;
            const bool jm0 = gj > 0, jmW = gj < W - 1;
            const float xC = xA[e + 1], xE = xA[e + 2], xW_ = xA[e];
            const float I0c = (imH ? xS[e + 1] - xC : 0.f) - r0C[e + 1];
            const float I0n = im0 ? (xC - xN[e] - r0N[e]) : 0.f;
            const float I0w = jm0 ? ((imH ? xS[e] - xW_ : 0.f) - r0C[e]) : 0.f;
            const float I1c = (jmW ? xE - xC : 0.f) - r1C[e + 1];
            const float I1w = jm0 ? (xC - xW_ - r1C[e]) : 0.f;
            const float I1s = imH ? ((jmW ? xS[e + 2] - xS[e + 1] : 0.f) - r1S[e]) : 0.f;
            const float g0 = I0c - I0n;
            const float g1 = jm0 ? (I0c - I0w) : 0.f;
            const float g2 = I1c - I1w;
            const float g3 = imH ? (I1s - I1c) : 0.f;
            const float up0 = u0o[e] + SIGMA * g0;
            const float up1 = u1o[e] + SIGMA * g1;
            const float up2 = u2o[e] + SIGMA * g2;
            const float up3 = u3o[e] + SIGMA * g3;
            const float nrm = sqrtf(up0 * up0 + up1 * up1 + up2 * up2 + up3 * up3);
            const float inv = 1.f / fmaxf(nrm * (1.0f / LAM2), 1.f);
            un0[e] = u0o[e] + RHO * (up0 * inv - u0o[e]);
            un1[e] = u1o[e] + RHO * (up1 * inv - u1o[e]);
            un2[e] = u2o[e] + RHO * (up2 * inv - u2o[e]);
            un3[e] = u3o[e] + RHO * (up3 * inv - u3o[e]);
        }
        const int p = cb + gi * W + gjb;
        if (MODE == 2) {
            #pragma unroll
            for (int e = 0; e < 4; ++e)
                *(float4*)(outp + 3 * CHW + 4 * (p + e)) =
                    make_float4(un0[e], un1[e], un2[e], un3[e]);
        } else {
            h4 o0, o1, o2, o3;
            #pragma unroll
            for (int e = 0; e < 4; ++e) {
                o0[e] = (f16)un0[e]; o1[e] = (f16)un1[e];
                o2[e] = (f16)un2[e]; o3[e] = (f16)un3[e];
            }
            *(h4*)(dstH + (HP_U + 0) * CHW + p) = o0;
            *(h4*)(dstH + (HP_U + 1) * CHW + p) = o1;
            *(h4*)(dstH + (HP_U + 2) * CHW + p) = o2;
            *(h4*)(dstH + (HP_U + 3) * CHW + p) = o3;
        }
    }
}

extern "C" void kernel_launch(void* const* d_in, const int* in_sizes, int n_in,
                              void* d_out, int out_size, void* d_ws, size_t ws_size,
                              hipStream_t stream) {
    const float* y = (const float*)d_in[0];
    float* out = (float*)d_out;

    // ws layout: x2 fp32 buf0 | x2 fp32 buf1 | h-buf0 (6*CHW f16) | h-buf1
    float* x0 = (float*)d_ws;
    float* x1 = x0 + CHW;
    f16*   h0 = (f16*)(x1 + CHW);
    f16*   h1 = h0 + 6 * CHW;

    dim3 blk(256, 1, 1);
    dim3 grd(W / TW, H / TH, C);    // (8, 64, 3) = 1536 blocks = 6/CU, 1 round

    fused_it<0><<<grd, blk, 0, stream>>>(y, nullptr, nullptr, x0, h0, nullptr);
    for (int k = 2; k < N_IT; ++k) {
        const bool even = (k % 2 == 0);
        float* sx = even ? x0 : x1;  f16* sh = even ? h0 : h1;
        float* dx = even ? x1 : x0;  f16* dh = even ? h1 : h0;
        fused_it<1><<<grd, blk, 0, stream>>>(y, sx, sh, dx, dh, nullptr);
    }
    fused_it<2><<<grd, blk, 0, stream>>>(y, x0, h0, nullptr, nullptr, out);
}